// Round 1
// baseline (2302.710 us; speedup 1.0000x reference)
//
#include <hip/hip_runtime.h>

#define N_TOK 16384
#define ALPHA_LRELU 0.2f
#define NEGV -9e15f
#define NSPLIT 3
#define LOG2E 1.44269504f

typedef _Float16 f16;
typedef __attribute__((ext_vector_type(8))) _Float16 f16x8;
typedef __attribute__((ext_vector_type(4))) float f32x4;
typedef __attribute__((ext_vector_type(4))) int i32x4;
typedef unsigned short u16;

__device__ __forceinline__ float bf2f(u16 b) {
  unsigned u = ((unsigned)b) << 16;
  return __builtin_bit_cast(float, u);
}
__device__ __forceinline__ f16x8 cvt8(i32x4 v) {
  f16x8 r;
#pragma unroll
  for (int i = 0; i < 4; ++i) {
    unsigned u = __builtin_bit_cast(unsigned, v[i]);
    r[2 * i]     = (f16)__builtin_bit_cast(float, (u & 0xffffu) << 16);
    r[2 * i + 1] = (f16)__builtin_bit_cast(float, u & 0xffff0000u);
  }
  return r;
}

// ---------------- kernel 0: input dtype detection (EVEN u16 parity) ----
__global__ __launch_bounds__(64) void detect_kernel(const u16* __restrict__ h16,
                                                    int* __restrict__ flag)
{
  int lane = threadIdx.x;
  unsigned u = h16[lane * 2];
  unsigned e = (u >> 7) & 0xFFu;
  int sane = (e >= 0x60u && e <= 0x8Eu) ? 1 : 0;
#pragma unroll
  for (int off = 32; off >= 1; off >>= 1) sane += __shfl_xor(sane, off);
  if (lane == 0) *flag = (sane >= 32) ? 1 : 0;  // 1 = bf16 inputs, 0 = fp32
}

// ---------------- kernel 0.5: ws-too-small sentinel ----------------
__global__ __launch_bounds__(256) void sentinel_kernel(float* __restrict__ out) {
  int i = blockIdx.x * 256 + threadIdx.x;
  if (i < N_TOK * 128) out[i] = 100.0f;
}

// ---------------- kernel 1: W transpose -> fp16 ----------------
// W_query additionally scaled by log2(e): scores arrive in log2 domain
// (leakyrelu commutes with positive scaling), so softmax uses exp2 directly.
__global__ __launch_bounds__(256) void wt_kernel(
    const int* __restrict__ flag,
    const void* __restrict__ Wq, const void* __restrict__ Wk,
    const void* __restrict__ Wv, f16* __restrict__ Wt)
{
  const int isbf = *flag;
  int w = blockIdx.y;
  const void* W = (w == 0) ? Wq : (w == 1) ? Wk : Wv;
  int idx = blockIdx.x * 256 + threadIdx.x;
  int k = idx >> 7, n = idx & 127;
  float v = isbf ? bf2f(((const u16*)W)[idx]) : ((const float*)W)[idx];
  if (w == 0) v *= LOG2E;
  Wt[w * 32768 + n * 256 + k] = (f16)v;
}

// ---------------- kernel 2: fused QKV GEMM ----------------
__global__ __launch_bounds__(256) void qkv_kernel(
    const int* __restrict__ flag, const void* __restrict__ hvp,
    const f16* __restrict__ Wt,
    f16* __restrict__ Qo, f16* __restrict__ Ko, f16* __restrict__ Vt)
{
  const int isbf = *flag;
  const int mb = blockIdx.x * 64;
  const int gy = blockIdx.y;
  const int tid = threadIdx.x;
  const int wave = tid >> 6, lane = tid & 63, quad = lane >> 4, l16 = lane & 15;

  __shared__ __align__(16) f16 hs[64][256 + 8];

  if (isbf) {
    const u16* h = (const u16*)hvp;
#pragma unroll
    for (int i = 0; i < 8; ++i) {
      int c = i * 256 + tid;
      int r = c >> 5, o = c & 31;
      i32x4 v = *(const i32x4*)(h + (size_t)(mb + r) * 256 + o * 8);
      *(f16x8*)(&hs[r][o * 8]) = cvt8(v);
    }
  } else {
    const float* h = (const float*)hvp;
#pragma unroll
    for (int i = 0; i < 8; ++i) {
      int c = i * 256 + tid;
      int r = c >> 5, o = c & 31;
      const float* p = h + (size_t)(mb + r) * 256 + o * 8;
      f32x4 v0 = *(const f32x4*)p, v1 = *(const f32x4*)(p + 4);
      f16x8 q;
#pragma unroll
      for (int j = 0; j < 4; ++j) { q[j] = (f16)v0[j]; q[4 + j] = (f16)v1[j]; }
      *(f16x8*)(&hs[r][o * 8]) = q;
    }
  }
  __syncthreads();

  const f16* Wg = Wt + gy * 32768;

  if (gy < 2) {
    f16x8 a[8];
#pragma unroll
    for (int ks = 0; ks < 8; ++ks)
      a[ks] = *(const f16x8*)(&hs[wave * 16 + l16][ks * 32 + quad * 8]);
    f32x4 acc[8];
#pragma unroll
    for (int ct = 0; ct < 8; ++ct) acc[ct] = (f32x4){0.f, 0.f, 0.f, 0.f};
#pragma unroll
    for (int ks = 0; ks < 8; ++ks)
#pragma unroll
      for (int ct = 0; ct < 8; ++ct) {
        f16x8 b = *(const f16x8*)(Wg + (ct * 16 + l16) * 256 + ks * 32 + quad * 8);
        acc[ct] = __builtin_amdgcn_mfma_f32_16x16x32_f16(a[ks], b, acc[ct], 0, 0, 0);
      }
    f16* O = (gy == 0) ? Qo : Ko;
#pragma unroll
    for (int ct = 0; ct < 8; ++ct)
#pragma unroll
      for (int r = 0; r < 4; ++r)
        O[(size_t)(mb + wave * 16 + quad * 4 + r) * 128 + ct * 16 + l16] = (f16)acc[ct][r];
  } else {
    f32x4 acc[2][4];
#pragma unroll
    for (int ft = 0; ft < 2; ++ft)
#pragma unroll
      for (int bt = 0; bt < 4; ++bt) acc[ft][bt] = (f32x4){0.f, 0.f, 0.f, 0.f};
#pragma unroll
    for (int ks = 0; ks < 8; ++ks) {
      f16x8 a2[2], b2[4];
#pragma unroll
      for (int ft = 0; ft < 2; ++ft)
        a2[ft] = *(const f16x8*)(Wg + ((wave * 2 + ft) * 16 + l16) * 256 + ks * 32 + quad * 8);
#pragma unroll
      for (int bt = 0; bt < 4; ++bt)
        b2[bt] = *(const f16x8*)(&hs[bt * 16 + l16][ks * 32 + quad * 8]);
#pragma unroll
      for (int ft = 0; ft < 2; ++ft)
#pragma unroll
        for (int bt = 0; bt < 4; ++bt)
          acc[ft][bt] = __builtin_amdgcn_mfma_f32_16x16x32_f16(a2[ft], b2[bt], acc[ft][bt], 0, 0, 0);
    }
#pragma unroll
    for (int ft = 0; ft < 2; ++ft)
#pragma unroll
      for (int bt = 0; bt < 4; ++bt)
#pragma unroll
        for (int r = 0; r < 4; ++r)
          Vt[(size_t)((wave * 2 + ft) * 16 + quad * 4 + r) * N_TOK + mb + bt * 16 + l16] =
              (f16)acc[ft][bt][r];
  }
}

// ---------------- kernel 3: flash attention, split-K x3, log2 domain ----
// adjacency ballot-packed to 1 bit in LDS: As16[64][4] (512 B) instead of
// As[64][68] int32 (17 KB) -> LDS/block 62.5 KB -> 44.5 KB -> 3 blocks/CU.
__global__ __launch_bounds__(256, 3) void flash_kernel(
    const f16* __restrict__ Q, const f16* __restrict__ Kg,
    const f16* __restrict__ Vt, const int* __restrict__ adj,
    float* __restrict__ Opart, float* __restrict__ mpart,
    float* __restrict__ lpart)
{
  const int qb = blockIdx.x * 64;
  const int ksec = blockIdx.y;
  const int base = 256 / NSPLIT;                 // 85
  const int rem  = 256 % NSPLIT;                 // 1
  const int iters = base + (ksec < rem ? 1 : 0); // 86,85,85
  const int tile0 = ksec * base + (ksec < rem ? ksec : rem);
  const int kb0 = tile0 * 64;
  const int tid = threadIdx.x;
  const int wave = tid >> 6, lane = tid & 63, quad = lane >> 4, l16 = lane & 15;

  __shared__ __align__(16) f16 Ks[64][136];
  __shared__ __align__(16) f16 Vs[128][72];
  __shared__ __align__(16) f16 Ps[4][16][72];
  __shared__ __align__(8)  u16 As16[64][4];

  f16x8 qf[4];
#pragma unroll
  for (int ks = 0; ks < 4; ++ks)
    qf[ks] = *(const f16x8*)(Q + (size_t)(qb + wave * 16 + l16) * 128 + ks * 32 + quad * 8);

  f16x8 ONES;
#pragma unroll
  for (int j = 0; j < 8; ++j) ONES[j] = (f16)1.0f;

  // mask-bit query shift: bit (l16&3)*16 + ct*4 + (l16>>2) of the packed row
  const int shq = (l16 & 3) * 16 + (l16 >> 2);

  f32x4 Oacc[8];
#pragma unroll
  for (int ot = 0; ot < 8; ++ot) Oacc[ot] = (f32x4){0.f, 0.f, 0.f, 0.f};
  f32x4 Lacc = (f32x4){0.f, 0.f, 0.f, 0.f};  // row-sum via MFMA-ones
  float m2[4];
#pragma unroll
  for (int r = 0; r < 4; ++r) m2[r] = -INFINITY;

  i32x4 pK[4], pV[4], pA[4];
#pragma unroll
  for (int i = 0; i < 4; ++i) {
    int c = i * 256 + tid;
    pK[i] = *(const i32x4*)(Kg + (size_t)(kb0 + (c >> 4)) * 128 + (c & 15) * 8);
    pV[i] = *(const i32x4*)(Vt + (size_t)(c >> 3) * N_TOK + kb0 + (c & 7) * 8);
    pA[i] = *(const i32x4*)(adj + (size_t)(qb + (c >> 4)) * N_TOK + kb0 + (c & 15) * 4);
  }

  for (int it = 0; it < iters; ++it) {
    __syncthreads();
#pragma unroll
    for (int i = 0; i < 4; ++i) {
      int c = i * 256 + tid;
      *(f16x8*)(&Ks[c >> 4][(c & 15) * 8]) = __builtin_bit_cast(f16x8, pK[i]);
      *(f16x8*)(&Vs[c >> 3][(c & 7) * 8])  = __builtin_bit_cast(f16x8, pV[i]);
      // ballot-pack adjacency: bit l of b_j = adj[row(i,wave,l>>4)][col (l&15)*4+j]
      unsigned long long b0 = __ballot(pA[i][0] > 0);
      unsigned long long b1 = __ballot(pA[i][1] > 0);
      unsigned long long b2 = __ballot(pA[i][2] > 0);
      unsigned long long b3 = __ballot(pA[i][3] > 0);
      if (lane < 16) {
        int j = lane & 3, g = lane >> 2;
        unsigned long long v = (j == 0) ? b0 : (j == 1) ? b1 : (j == 2) ? b2 : b3;
        As16[i * 16 + wave * 4 + g][j] = (u16)(v >> (16 * g));
      }
    }
    __syncthreads();
    if (it + 1 < iters) {
      int kb = kb0 + (it + 1) * 64;
#pragma unroll
      for (int i = 0; i < 4; ++i) {
        int c = i * 256 + tid;
        pK[i] = *(const i32x4*)(Kg + (size_t)(kb + (c >> 4)) * 128 + (c & 15) * 8);
        pV[i] = *(const i32x4*)(Vt + (size_t)(c >> 3) * N_TOK + kb + (c & 7) * 8);
        pA[i] = *(const i32x4*)(adj + (size_t)(qb + (c >> 4)) * N_TOK + kb + (c & 15) * 4);
      }
    }

    // S(log2 domain) = Q K^T, leakyrelu
    float sc[4][4];
#pragma unroll
    for (int ct = 0; ct < 4; ++ct) {
      f32x4 s = (f32x4){0.f, 0.f, 0.f, 0.f};
#pragma unroll
      for (int ks = 0; ks < 4; ++ks) {
        f16x8 b = *(const f16x8*)(&Ks[ct * 16 + l16][ks * 32 + quad * 8]);
        s = __builtin_amdgcn_mfma_f32_16x16x32_f16(qf[ks], b, s, 0, 0, 0);
      }
#pragma unroll
      for (int r = 0; r < 4; ++r) {
        float v = s[r];
        sc[ct][r] = fmaxf(v, ALPHA_LRELU * v);
      }
    }
    // adjacency mask from packed bits (broadcast b64 read per row)
#pragma unroll
    for (int r = 0; r < 4; ++r) {
      unsigned long long a64 =
          *(const unsigned long long*)(&As16[wave * 16 + quad * 4 + r][0]);
      unsigned y = (unsigned)(a64 >> shq);
#pragma unroll
      for (int ct = 0; ct < 4; ++ct)
        if (!((y >> (4 * ct)) & 1u)) sc[ct][r] = NEGV;
    }

    // tile row max (16-lane butterfly within quad)
    float mx[4];
#pragma unroll
    for (int r = 0; r < 4; ++r) {
      float m = fmaxf(fmaxf(sc[0][r], sc[1][r]), fmaxf(sc[2][r], sc[3][r]));
#pragma unroll
      for (int off = 8; off >= 1; off >>= 1)
        m = fmaxf(m, __shfl_xor(m, off, 16));
      mx[r] = m;
    }
    // wave-uniform skip: rescale only if some row's max improved
    bool up = (mx[0] > m2[0]) | (mx[1] > m2[1]) | (mx[2] > m2[2]) | (mx[3] > m2[3]);
    if (__ballot(up)) {
      float al[4];
#pragma unroll
      for (int r = 0; r < 4; ++r) {
        float mn = fmaxf(m2[r], mx[r]);
        al[r] = exp2f(m2[r] - mn);
        m2[r] = mn;
      }
#pragma unroll
      for (int ot = 0; ot < 8; ++ot)
#pragma unroll
        for (int r = 0; r < 4; ++r) Oacc[ot][r] *= al[r];
#pragma unroll
      for (int r = 0; r < 4; ++r) Lacc[r] *= al[r];
    }

    // P = exp2(sc - m2), to LDS (C-layout -> A-layout round trip)
#pragma unroll
    for (int ct = 0; ct < 4; ++ct)
#pragma unroll
      for (int r = 0; r < 4; ++r)
        Ps[wave][quad * 4 + r][ct * 16 + l16] = (f16)exp2f(sc[ct][r] - m2[r]);

    asm volatile("s_waitcnt lgkmcnt(0)" ::: "memory");
    f16x8 pa0 = *(const f16x8*)(&Ps[wave][l16][quad * 8]);
    f16x8 pa1 = *(const f16x8*)(&Ps[wave][l16][32 + quad * 8]);
#pragma unroll
    for (int ot = 0; ot < 8; ++ot) {
      f16x8 b0 = *(const f16x8*)(&Vs[ot * 16 + l16][quad * 8]);
      f16x8 b1 = *(const f16x8*)(&Vs[ot * 16 + l16][32 + quad * 8]);
      Oacc[ot] = __builtin_amdgcn_mfma_f32_16x16x32_f16(pa0, b0, Oacc[ot], 0, 0, 0);
      Oacc[ot] = __builtin_amdgcn_mfma_f32_16x16x32_f16(pa1, b1, Oacc[ot], 0, 0, 0);
    }
    // row-sum of P via all-ones B (every lane gets the sum)
    Lacc = __builtin_amdgcn_mfma_f32_16x16x32_f16(pa0, ONES, Lacc, 0, 0, 0);
    Lacc = __builtin_amdgcn_mfma_f32_16x16x32_f16(pa1, ONES, Lacc, 0, 0, 0);
  }

  float* Op = Opart + (size_t)ksec * (N_TOK * 128);
#pragma unroll
  for (int ot = 0; ot < 8; ++ot)
#pragma unroll
    for (int r = 0; r < 4; ++r) {
      int row = qb + wave * 16 + quad * 4 + r;
      Op[(size_t)row * 128 + ot * 16 + l16] = Oacc[ot][r];
    }
  if (l16 == 0) {
#pragma unroll
    for (int r = 0; r < 4; ++r) {
      int row = qb + wave * 16 + quad * 4 + r;
      mpart[ksec * N_TOK + row] = m2[r];   // log2-domain max
      lpart[ksec * N_TOK + row] = Lacc[r];
    }
  }
}

// ---------------- kernel 4: split-K combine + elu (log2 domain) --------
__global__ __launch_bounds__(256) void combine_kernel(
    const float* __restrict__ Opart, const float* __restrict__ mpart,
    const float* __restrict__ lpart, float* __restrict__ out)
{
  const int qb = blockIdx.x * 64;
  const int t = threadIdx.x;
  __shared__ float sa[NSPLIT][64], sdn[64];
  if (t < 64) {
    float m = -INFINITY;
#pragma unroll
    for (int s = 0; s < NSPLIT; ++s) m = fmaxf(m, mpart[s * N_TOK + qb + t]);
    float dn = 0.f;
#pragma unroll
    for (int s = 0; s < NSPLIT; ++s) {
      float a = exp2f(mpart[s * N_TOK + qb + t] - m);
      sa[s][t] = a;
      dn += lpart[s * N_TOK + qb + t] * a;
    }
    sdn[t] = 1.0f / dn;
  }
  __syncthreads();
  float* Og = out + (size_t)qb * 128;
#pragma unroll
  for (int i = 0; i < 8; ++i) {
    int idx = (i * 256 + t) * 4;
    int row = idx >> 7;
    f32x4 acc = (f32x4){0.f, 0.f, 0.f, 0.f};
#pragma unroll
    for (int s = 0; s < NSPLIT; ++s) {
      f32x4 o = *(const f32x4*)(Opart + (size_t)s * (N_TOK * 128) + (size_t)qb * 128 + idx);
      float a = sa[s][row];
#pragma unroll
      for (int j = 0; j < 4; ++j) acc[j] += o[j] * a;
    }
    float dn = sdn[row];
    f32x4 v;
#pragma unroll
    for (int j = 0; j < 4; ++j) {
      float x = acc[j] * dn;
      v[j] = (x > 0.f) ? x : (__expf(x) - 1.f);
    }
    *(f32x4*)(Og + idx) = v;
  }
}

// ---------------- fallback: single-pass flash (ws too small) ----------
__global__ __launch_bounds__(256) void flash1_kernel(
    const f16* __restrict__ Q, const f16* __restrict__ Kg,
    const f16* __restrict__ Vt, const int* __restrict__ adj,
    float* __restrict__ out)
{
  const int qb = blockIdx.x * 64;
  const int tid = threadIdx.x;
  const int wave = tid >> 6, lane = tid & 63, quad = lane >> 4, l16 = lane & 15;

  __shared__ __align__(16) f16 Ks[64][136];
  __shared__ __align__(16) f16 Vs[128][72];
  __shared__ __align__(16) int As[64][68];
  __shared__ __align__(16) f16 Ps[4][16][72];

  f16x8 qf[4];
#pragma unroll
  for (int ks = 0; ks < 4; ++ks)
    qf[ks] = *(const f16x8*)(Q + (size_t)(qb + wave * 16 + l16) * 128 + ks * 32 + quad * 8);
  f16x8 ONES;
#pragma unroll
  for (int j = 0; j < 8; ++j) ONES[j] = (f16)1.0f;

  f32x4 Oacc[8];
#pragma unroll
  for (int ot = 0; ot < 8; ++ot) Oacc[ot] = (f32x4){0.f, 0.f, 0.f, 0.f};
  f32x4 Lacc = (f32x4){0.f, 0.f, 0.f, 0.f};
  float m2[4];
#pragma unroll
  for (int r = 0; r < 4; ++r) m2[r] = -INFINITY;

  i32x4 pK[4], pV[4], pA[4];
#pragma unroll
  for (int i = 0; i < 4; ++i) {
    int c = i * 256 + tid;
    pK[i] = *(const i32x4*)(Kg + (size_t)(c >> 4) * 128 + (c & 15) * 8);
    pV[i] = *(const i32x4*)(Vt + (size_t)(c >> 3) * N_TOK + (c & 7) * 8);
    pA[i] = *(const i32x4*)(adj + (size_t)(qb + (c >> 4)) * N_TOK + (c & 15) * 4);
  }

  for (int it = 0; it < 256; ++it) {
    __syncthreads();
#pragma unroll
    for (int i = 0; i < 4; ++i) {
      int c = i * 256 + tid;
      *(f16x8*)(&Ks[c >> 4][(c & 15) * 8]) = __builtin_bit_cast(f16x8, pK[i]);
      *(f16x8*)(&Vs[c >> 3][(c & 7) * 8])  = __builtin_bit_cast(f16x8, pV[i]);
      *(i32x4*)(&As[c >> 4][(c & 15) * 4]) = pA[i];
    }
    __syncthreads();
    if (it + 1 < 256) {
      int kb = (it + 1) * 64;
#pragma unroll
      for (int i = 0; i < 4; ++i) {
        int c = i * 256 + tid;
        pK[i] = *(const i32x4*)(Kg + (size_t)(kb + (c >> 4)) * 128 + (c & 15) * 8);
        pV[i] = *(const i32x4*)(Vt + (size_t)(c >> 3) * N_TOK + kb + (c & 7) * 8);
        pA[i] = *(const i32x4*)(adj + (size_t)(qb + (c >> 4)) * N_TOK + kb + (c & 15) * 4);
      }
    }
    float sc[4][4];
#pragma unroll
    for (int ct = 0; ct < 4; ++ct) {
      f32x4 s = (f32x4){0.f, 0.f, 0.f, 0.f};
#pragma unroll
      for (int ks = 0; ks < 4; ++ks) {
        f16x8 b = *(const f16x8*)(&Ks[ct * 16 + l16][ks * 32 + quad * 8]);
        s = __builtin_amdgcn_mfma_f32_16x16x32_f16(qf[ks], b, s, 0, 0, 0);
      }
#pragma unroll
      for (int r = 0; r < 4; ++r) {
        float v = s[r];
        v = fmaxf(v, ALPHA_LRELU * v);
        sc[ct][r] = (As[wave * 16 + quad * 4 + r][ct * 16 + l16] > 0) ? v : NEGV;
      }
    }
    float mx[4];
#pragma unroll
    for (int r = 0; r < 4; ++r) {
      float m = fmaxf(fmaxf(sc[0][r], sc[1][r]), fmaxf(sc[2][r], sc[3][r]));
#pragma unroll
      for (int off = 8; off >= 1; off >>= 1)
        m = fmaxf(m, __shfl_xor(m, off, 16));
      mx[r] = m;
    }
    bool up = (mx[0] > m2[0]) | (mx[1] > m2[1]) | (mx[2] > m2[2]) | (mx[3] > m2[3]);
    if (__ballot(up)) {
      float al[4];
#pragma unroll
      for (int r = 0; r < 4; ++r) {
        float mn = fmaxf(m2[r], mx[r]);
        al[r] = exp2f(m2[r] - mn);
        m2[r] = mn;
      }
#pragma unroll
      for (int ot = 0; ot < 8; ++ot)
#pragma unroll
        for (int r = 0; r < 4; ++r) Oacc[ot][r] *= al[r];
#pragma unroll
      for (int r = 0; r < 4; ++r) Lacc[r] *= al[r];
    }
#pragma unroll
    for (int ct = 0; ct < 4; ++ct)
#pragma unroll
      for (int r = 0; r < 4; ++r)
        Ps[wave][quad * 4 + r][ct * 16 + l16] = (f16)exp2f(sc[ct][r] - m2[r]);

    asm volatile("s_waitcnt lgkmcnt(0)" ::: "memory");
    f16x8 pa0 = *(const f16x8*)(&Ps[wave][l16][quad * 8]);
    f16x8 pa1 = *(const f16x8*)(&Ps[wave][l16][32 + quad * 8]);
#pragma unroll
    for (int ot = 0; ot < 8; ++ot) {
      f16x8 b0 = *(const f16x8*)(&Vs[ot * 16 + l16][quad * 8]);
      f16x8 b1 = *(const f16x8*)(&Vs[ot * 16 + l16][32 + quad * 8]);
      Oacc[ot] = __builtin_amdgcn_mfma_f32_16x16x32_f16(pa0, b0, Oacc[ot], 0, 0, 0);
      Oacc[ot] = __builtin_amdgcn_mfma_f32_16x16x32_f16(pa1, b1, Oacc[ot], 0, 0, 0);
    }
    Lacc = __builtin_amdgcn_mfma_f32_16x16x32_f16(pa0, ONES, Lacc, 0, 0, 0);
    Lacc = __builtin_amdgcn_mfma_f32_16x16x32_f16(pa1, ONES, Lacc, 0, 0, 0);
  }
#pragma unroll
  for (int ot = 0; ot < 8; ++ot)
#pragma unroll
    for (int r = 0; r < 4; ++r) {
      float v = Oacc[ot][r] / Lacc[r];
      v = (v > 0.f) ? v : (__expf(v) - 1.f);
      int row = qb + wave * 16 + quad * 4 + r;
      out[(size_t)row * 128 + ot * 16 + l16] = v;
    }
}

extern "C" void kernel_launch(void* const* d_in, const int* in_sizes, int n_in,
                              void* d_out, int out_size, void* d_ws, size_t ws_size,
                              hipStream_t stream)
{
  const void* h  = d_in[0];
  const int* adj = (const int*)d_in[1];
  const void* Wq = d_in[2];
  const void* Wk = d_in[3];
  const void* Wv = d_in[4];
  float* out = (float*)d_out;             // fp32 [16384][128]

  char* ws = (char*)d_ws;
  int* flag = (int*)ws;                    // @0
  f16* Wt = (f16*)(ws + 1024);             // 196608 B
  f16* Q  = (f16*)(ws + 262144);           // 4 MiB
  f16* K  = (f16*)(ws + 4456448);          // 4 MiB
  f16* Vt = (f16*)(ws + 8650752);          // 4 MiB -> 12845056
  float* Opart = (float*)(ws + 12845056);  // 3 x 16384 x 128 f32 = 24 MiB
  float* mpart = (float*)(ws + 38010880);  // 3 x 16384 f32
  float* lpart = (float*)(ws + 38207488);  // 3 x 16384 f32 -> 38404096
  const size_t NEED_BASE  = 12845056;
  const size_t NEED_SPLIT = 38404096;

  if (ws_size < NEED_BASE) {
    sentinel_kernel<<<(N_TOK * 128 + 255) / 256, 256, 0, stream>>>(out);
    return;
  }

  detect_kernel<<<1, 64, 0, stream>>>((const u16*)h, flag);
  wt_kernel<<<dim3(128, 3), 256, 0, stream>>>(flag, Wq, Wk, Wv, Wt);
  qkv_kernel<<<dim3(256, 3), 256, 0, stream>>>(flag, h, Wt, Q, K, Vt);

  if (ws_size >= NEED_SPLIT) {
    // split-K x3: 768 blocks -> exactly 3 blocks/CU (LDS 44.5 KB/block)
    flash_kernel<<<dim3(256, NSPLIT), 256, 0, stream>>>(Q, K, Vt, adj,
                                                        Opart, mpart, lpart);
    combine_kernel<<<dim3(256), 256, 0, stream>>>(Opart, mpart, lpart, out);
  } else {
    flash1_kernel<<<dim3(256), 256, 0, stream>>>(Q, K, Vt, adj, out);
  }
}

// Round 2
// 1785.595 us; speedup vs baseline: 1.2896x; 1.2896x over previous
//
#include <hip/hip_runtime.h>

#define N_TOK 16384
#define ALPHA_LRELU 0.2f
#define NEGV -9e15f
#define NSPLIT 3
#define LOG2E 1.44269504f

typedef _Float16 f16;
typedef __attribute__((ext_vector_type(8))) _Float16 f16x8;
typedef __attribute__((ext_vector_type(4))) float f32x4;
typedef __attribute__((ext_vector_type(4))) int i32x4;
typedef unsigned short u16;

__device__ __forceinline__ float bf2f(u16 b) {
  unsigned u = ((unsigned)b) << 16;
  return __builtin_bit_cast(float, u);
}
__device__ __forceinline__ f16x8 cvt8(i32x4 v) {
  f16x8 r;
#pragma unroll
  for (int i = 0; i < 4; ++i) {
    unsigned u = __builtin_bit_cast(unsigned, v[i]);
    r[2 * i]     = (f16)__builtin_bit_cast(float, (u & 0xffffu) << 16);
    r[2 * i + 1] = (f16)__builtin_bit_cast(float, u & 0xffff0000u);
  }
  return r;
}

// ---------------- kernel 0: input dtype detection (EVEN u16 parity) ----
__global__ __launch_bounds__(64) void detect_kernel(const u16* __restrict__ h16,
                                                    int* __restrict__ flag)
{
  int lane = threadIdx.x;
  unsigned u = h16[lane * 2];
  unsigned e = (u >> 7) & 0xFFu;
  int sane = (e >= 0x60u && e <= 0x8Eu) ? 1 : 0;
#pragma unroll
  for (int off = 32; off >= 1; off >>= 1) sane += __shfl_xor(sane, off);
  if (lane == 0) *flag = (sane >= 32) ? 1 : 0;  // 1 = bf16 inputs, 0 = fp32
}

// ---------------- kernel 0.5: ws-too-small sentinel ----------------
__global__ __launch_bounds__(256) void sentinel_kernel(float* __restrict__ out) {
  int i = blockIdx.x * 256 + threadIdx.x;
  if (i < N_TOK * 128) out[i] = 100.0f;
}

// ---------------- kernel 1: W transpose -> fp16 ----------------
// W_query additionally scaled by log2(e): scores arrive in log2 domain
// (leakyrelu commutes with positive scaling), so softmax uses exp2 directly.
__global__ __launch_bounds__(256) void wt_kernel(
    const int* __restrict__ flag,
    const void* __restrict__ Wq, const void* __restrict__ Wk,
    const void* __restrict__ Wv, f16* __restrict__ Wt)
{
  const int isbf = *flag;
  int w = blockIdx.y;
  const void* W = (w == 0) ? Wq : (w == 1) ? Wk : Wv;
  int idx = blockIdx.x * 256 + threadIdx.x;
  int k = idx >> 7, n = idx & 127;
  float v = isbf ? bf2f(((const u16*)W)[idx]) : ((const float*)W)[idx];
  if (w == 0) v *= LOG2E;
  Wt[w * 32768 + n * 256 + k] = (f16)v;
}

// ---------------- kernel 2: fused QKV GEMM ----------------
__global__ __launch_bounds__(256) void qkv_kernel(
    const int* __restrict__ flag, const void* __restrict__ hvp,
    const f16* __restrict__ Wt,
    f16* __restrict__ Qo, f16* __restrict__ Ko, f16* __restrict__ Vt)
{
  const int isbf = *flag;
  const int mb = blockIdx.x * 64;
  const int gy = blockIdx.y;
  const int tid = threadIdx.x;
  const int wave = tid >> 6, lane = tid & 63, quad = lane >> 4, l16 = lane & 15;

  __shared__ __align__(16) f16 hs[64][256 + 8];

  if (isbf) {
    const u16* h = (const u16*)hvp;
#pragma unroll
    for (int i = 0; i < 8; ++i) {
      int c = i * 256 + tid;
      int r = c >> 5, o = c & 31;
      i32x4 v = *(const i32x4*)(h + (size_t)(mb + r) * 256 + o * 8);
      *(f16x8*)(&hs[r][o * 8]) = cvt8(v);
    }
  } else {
    const float* h = (const float*)hvp;
#pragma unroll
    for (int i = 0; i < 8; ++i) {
      int c = i * 256 + tid;
      int r = c >> 5, o = c & 31;
      const float* p = h + (size_t)(mb + r) * 256 + o * 8;
      f32x4 v0 = *(const f32x4*)p, v1 = *(const f32x4*)(p + 4);
      f16x8 q;
#pragma unroll
      for (int j = 0; j < 4; ++j) { q[j] = (f16)v0[j]; q[4 + j] = (f16)v1[j]; }
      *(f16x8*)(&hs[r][o * 8]) = q;
    }
  }
  __syncthreads();

  const f16* Wg = Wt + gy * 32768;

  if (gy < 2) {
    f16x8 a[8];
#pragma unroll
    for (int ks = 0; ks < 8; ++ks)
      a[ks] = *(const f16x8*)(&hs[wave * 16 + l16][ks * 32 + quad * 8]);
    f32x4 acc[8];
#pragma unroll
    for (int ct = 0; ct < 8; ++ct) acc[ct] = (f32x4){0.f, 0.f, 0.f, 0.f};
#pragma unroll
    for (int ks = 0; ks < 8; ++ks)
#pragma unroll
      for (int ct = 0; ct < 8; ++ct) {
        f16x8 b = *(const f16x8*)(Wg + (ct * 16 + l16) * 256 + ks * 32 + quad * 8);
        acc[ct] = __builtin_amdgcn_mfma_f32_16x16x32_f16(a[ks], b, acc[ct], 0, 0, 0);
      }
    f16* O = (gy == 0) ? Qo : Ko;
#pragma unroll
    for (int ct = 0; ct < 8; ++ct)
#pragma unroll
      for (int r = 0; r < 4; ++r)
        O[(size_t)(mb + wave * 16 + quad * 4 + r) * 128 + ct * 16 + l16] = (f16)acc[ct][r];
  } else {
    f32x4 acc[2][4];
#pragma unroll
    for (int ft = 0; ft < 2; ++ft)
#pragma unroll
      for (int bt = 0; bt < 4; ++bt) acc[ft][bt] = (f32x4){0.f, 0.f, 0.f, 0.f};
#pragma unroll
    for (int ks = 0; ks < 8; ++ks) {
      f16x8 a2[2], b2[4];
#pragma unroll
      for (int ft = 0; ft < 2; ++ft)
        a2[ft] = *(const f16x8*)(Wg + ((wave * 2 + ft) * 16 + l16) * 256 + ks * 32 + quad * 8);
#pragma unroll
      for (int bt = 0; bt < 4; ++bt)
        b2[bt] = *(const f16x8*)(&hs[bt * 16 + l16][ks * 32 + quad * 8]);
#pragma unroll
      for (int ft = 0; ft < 2; ++ft)
#pragma unroll
        for (int bt = 0; bt < 4; ++bt)
          acc[ft][bt] = __builtin_amdgcn_mfma_f32_16x16x32_f16(a2[ft], b2[bt], acc[ft][bt], 0, 0, 0);
    }
#pragma unroll
    for (int ft = 0; ft < 2; ++ft)
#pragma unroll
      for (int bt = 0; bt < 4; ++bt)
#pragma unroll
        for (int r = 0; r < 4; ++r)
          Vt[(size_t)((wave * 2 + ft) * 16 + quad * 4 + r) * N_TOK + mb + bt * 16 + l16] =
              (f16)acc[ft][bt][r];
  }
}

// ---------------- kernel 3: flash attention, split-K x3, log2 domain ----
// adjacency ballot-packed to 1 bit in LDS: As16[64][4] (512 B) instead of
// As[64][68] int32 (17 KB) -> LDS/block 62.5 KB -> 44.5 KB -> 3 blocks/CU.
// NOTE: no waves-per-EU hint here. (256,3) made regalloc drop to 84 VGPRs,
// spilling the pK/pV/pA prefetch pipeline to scratch (+1.3 GB writes/dispatch,
// flash 981 -> 1191 us). Occupancy is LDS-limited at 3 blocks/CU either way.
__global__ __launch_bounds__(256) void flash_kernel(
    const f16* __restrict__ Q, const f16* __restrict__ Kg,
    const f16* __restrict__ Vt, const int* __restrict__ adj,
    float* __restrict__ Opart, float* __restrict__ mpart,
    float* __restrict__ lpart)
{
  const int qb = blockIdx.x * 64;
  const int ksec = blockIdx.y;
  const int base = 256 / NSPLIT;                 // 85
  const int rem  = 256 % NSPLIT;                 // 1
  const int iters = base + (ksec < rem ? 1 : 0); // 86,85,85
  const int tile0 = ksec * base + (ksec < rem ? ksec : rem);
  const int kb0 = tile0 * 64;
  const int tid = threadIdx.x;
  const int wave = tid >> 6, lane = tid & 63, quad = lane >> 4, l16 = lane & 15;

  __shared__ __align__(16) f16 Ks[64][136];
  __shared__ __align__(16) f16 Vs[128][72];
  __shared__ __align__(16) f16 Ps[4][16][72];
  __shared__ __align__(8)  u16 As16[64][4];

  f16x8 qf[4];
#pragma unroll
  for (int ks = 0; ks < 4; ++ks)
    qf[ks] = *(const f16x8*)(Q + (size_t)(qb + wave * 16 + l16) * 128 + ks * 32 + quad * 8);

  f16x8 ONES;
#pragma unroll
  for (int j = 0; j < 8; ++j) ONES[j] = (f16)1.0f;

  // mask-bit query shift: bit (l16&3)*16 + ct*4 + (l16>>2) of the packed row
  const int shq = (l16 & 3) * 16 + (l16 >> 2);

  f32x4 Oacc[8];
#pragma unroll
  for (int ot = 0; ot < 8; ++ot) Oacc[ot] = (f32x4){0.f, 0.f, 0.f, 0.f};
  f32x4 Lacc = (f32x4){0.f, 0.f, 0.f, 0.f};  // row-sum via MFMA-ones
  float m2[4];
#pragma unroll
  for (int r = 0; r < 4; ++r) m2[r] = -INFINITY;

  i32x4 pK[4], pV[4], pA[4];
#pragma unroll
  for (int i = 0; i < 4; ++i) {
    int c = i * 256 + tid;
    pK[i] = *(const i32x4*)(Kg + (size_t)(kb0 + (c >> 4)) * 128 + (c & 15) * 8);
    pV[i] = *(const i32x4*)(Vt + (size_t)(c >> 3) * N_TOK + kb0 + (c & 7) * 8);
    pA[i] = *(const i32x4*)(adj + (size_t)(qb + (c >> 4)) * N_TOK + kb0 + (c & 15) * 4);
  }

  for (int it = 0; it < iters; ++it) {
    __syncthreads();
#pragma unroll
    for (int i = 0; i < 4; ++i) {
      int c = i * 256 + tid;
      *(f16x8*)(&Ks[c >> 4][(c & 15) * 8]) = __builtin_bit_cast(f16x8, pK[i]);
      *(f16x8*)(&Vs[c >> 3][(c & 7) * 8])  = __builtin_bit_cast(f16x8, pV[i]);
      // ballot-pack adjacency: bit l of b_j = adj[row(i,wave,l>>4)][col (l&15)*4+j]
      unsigned long long b0 = __ballot(pA[i][0] > 0);
      unsigned long long b1 = __ballot(pA[i][1] > 0);
      unsigned long long b2 = __ballot(pA[i][2] > 0);
      unsigned long long b3 = __ballot(pA[i][3] > 0);
      if (lane < 16) {
        int j = lane & 3, g = lane >> 2;
        unsigned long long v = (j == 0) ? b0 : (j == 1) ? b1 : (j == 2) ? b2 : b3;
        As16[i * 16 + wave * 4 + g][j] = (u16)(v >> (16 * g));
      }
    }
    __syncthreads();
    if (it + 1 < iters) {
      int kb = kb0 + (it + 1) * 64;
#pragma unroll
      for (int i = 0; i < 4; ++i) {
        int c = i * 256 + tid;
        pK[i] = *(const i32x4*)(Kg + (size_t)(kb + (c >> 4)) * 128 + (c & 15) * 8);
        pV[i] = *(const i32x4*)(Vt + (size_t)(c >> 3) * N_TOK + kb + (c & 7) * 8);
        pA[i] = *(const i32x4*)(adj + (size_t)(qb + (c >> 4)) * N_TOK + kb + (c & 15) * 4);
      }
    }

    // S(log2 domain) = Q K^T, leakyrelu
    float sc[4][4];
#pragma unroll
    for (int ct = 0; ct < 4; ++ct) {
      f32x4 s = (f32x4){0.f, 0.f, 0.f, 0.f};
#pragma unroll
      for (int ks = 0; ks < 4; ++ks) {
        f16x8 b = *(const f16x8*)(&Ks[ct * 16 + l16][ks * 32 + quad * 8]);
        s = __builtin_amdgcn_mfma_f32_16x16x32_f16(qf[ks], b, s, 0, 0, 0);
      }
#pragma unroll
      for (int r = 0; r < 4; ++r) {
        float v = s[r];
        sc[ct][r] = fmaxf(v, ALPHA_LRELU * v);
      }
    }
    // adjacency mask from packed bits (broadcast b64 read per row)
#pragma unroll
    for (int r = 0; r < 4; ++r) {
      unsigned long long a64 =
          *(const unsigned long long*)(&As16[wave * 16 + quad * 4 + r][0]);
      unsigned y = (unsigned)(a64 >> shq);
#pragma unroll
      for (int ct = 0; ct < 4; ++ct)
        if (!((y >> (4 * ct)) & 1u)) sc[ct][r] = NEGV;
    }

    // tile row max (16-lane butterfly within quad)
    float mx[4];
#pragma unroll
    for (int r = 0; r < 4; ++r) {
      float m = fmaxf(fmaxf(sc[0][r], sc[1][r]), fmaxf(sc[2][r], sc[3][r]));
#pragma unroll
      for (int off = 8; off >= 1; off >>= 1)
        m = fmaxf(m, __shfl_xor(m, off, 16));
      mx[r] = m;
    }
    // wave-uniform skip: rescale only if some row's max improved
    bool up = (mx[0] > m2[0]) | (mx[1] > m2[1]) | (mx[2] > m2[2]) | (mx[3] > m2[3]);
    if (__ballot(up)) {
      float al[4];
#pragma unroll
      for (int r = 0; r < 4; ++r) {
        float mn = fmaxf(m2[r], mx[r]);
        al[r] = exp2f(m2[r] - mn);
        m2[r] = mn;
      }
#pragma unroll
      for (int ot = 0; ot < 8; ++ot)
#pragma unroll
        for (int r = 0; r < 4; ++r) Oacc[ot][r] *= al[r];
#pragma unroll
      for (int r = 0; r < 4; ++r) Lacc[r] *= al[r];
    }

    // P = exp2(sc - m2), to LDS (C-layout -> A-layout round trip)
#pragma unroll
    for (int ct = 0; ct < 4; ++ct)
#pragma unroll
      for (int r = 0; r < 4; ++r)
        Ps[wave][quad * 4 + r][ct * 16 + l16] = (f16)exp2f(sc[ct][r] - m2[r]);

    asm volatile("s_waitcnt lgkmcnt(0)" ::: "memory");
    f16x8 pa0 = *(const f16x8*)(&Ps[wave][l16][quad * 8]);
    f16x8 pa1 = *(const f16x8*)(&Ps[wave][l16][32 + quad * 8]);
#pragma unroll
    for (int ot = 0; ot < 8; ++ot) {
      f16x8 b0 = *(const f16x8*)(&Vs[ot * 16 + l16][quad * 8]);
      f16x8 b1 = *(const f16x8*)(&Vs[ot * 16 + l16][32 + quad * 8]);
      Oacc[ot] = __builtin_amdgcn_mfma_f32_16x16x32_f16(pa0, b0, Oacc[ot], 0, 0, 0);
      Oacc[ot] = __builtin_amdgcn_mfma_f32_16x16x32_f16(pa1, b1, Oacc[ot], 0, 0, 0);
    }
    // row-sum of P via all-ones B (every lane gets the sum)
    Lacc = __builtin_amdgcn_mfma_f32_16x16x32_f16(pa0, ONES, Lacc, 0, 0, 0);
    Lacc = __builtin_amdgcn_mfma_f32_16x16x32_f16(pa1, ONES, Lacc, 0, 0, 0);
  }

  float* Op = Opart + (size_t)ksec * (N_TOK * 128);
#pragma unroll
  for (int ot = 0; ot < 8; ++ot)
#pragma unroll
    for (int r = 0; r < 4; ++r) {
      int row = qb + wave * 16 + quad * 4 + r;
      Op[(size_t)row * 128 + ot * 16 + l16] = Oacc[ot][r];
    }
  if (l16 == 0) {
#pragma unroll
    for (int r = 0; r < 4; ++r) {
      int row = qb + wave * 16 + quad * 4 + r;
      mpart[ksec * N_TOK + row] = m2[r];   // log2-domain max
      lpart[ksec * N_TOK + row] = Lacc[r];
    }
  }
}

// ---------------- kernel 4: split-K combine + elu (log2 domain) --------
__global__ __launch_bounds__(256) void combine_kernel(
    const float* __restrict__ Opart, const float* __restrict__ mpart,
    const float* __restrict__ lpart, float* __restrict__ out)
{
  const int qb = blockIdx.x * 64;
  const int t = threadIdx.x;
  __shared__ float sa[NSPLIT][64], sdn[64];
  if (t < 64) {
    float m = -INFINITY;
#pragma unroll
    for (int s = 0; s < NSPLIT; ++s) m = fmaxf(m, mpart[s * N_TOK + qb + t]);
    float dn = 0.f;
#pragma unroll
    for (int s = 0; s < NSPLIT; ++s) {
      float a = exp2f(mpart[s * N_TOK + qb + t] - m);
      sa[s][t] = a;
      dn += lpart[s * N_TOK + qb + t] * a;
    }
    sdn[t] = 1.0f / dn;
  }
  __syncthreads();
  float* Og = out + (size_t)qb * 128;
#pragma unroll
  for (int i = 0; i < 8; ++i) {
    int idx = (i * 256 + t) * 4;
    int row = idx >> 7;
    f32x4 acc = (f32x4){0.f, 0.f, 0.f, 0.f};
#pragma unroll
    for (int s = 0; s < NSPLIT; ++s) {
      f32x4 o = *(const f32x4*)(Opart + (size_t)s * (N_TOK * 128) + (size_t)qb * 128 + idx);
      float a = sa[s][row];
#pragma unroll
      for (int j = 0; j < 4; ++j) acc[j] += o[j] * a;
    }
    float dn = sdn[row];
    f32x4 v;
#pragma unroll
    for (int j = 0; j < 4; ++j) {
      float x = acc[j] * dn;
      v[j] = (x > 0.f) ? x : (__expf(x) - 1.f);
    }
    *(f32x4*)(Og + idx) = v;
  }
}

// ---------------- fallback: single-pass flash (ws too small) ----------
__global__ __launch_bounds__(256) void flash1_kernel(
    const f16* __restrict__ Q, const f16* __restrict__ Kg,
    const f16* __restrict__ Vt, const int* __restrict__ adj,
    float* __restrict__ out)
{
  const int qb = blockIdx.x * 64;
  const int tid = threadIdx.x;
  const int wave = tid >> 6, lane = tid & 63, quad = lane >> 4, l16 = lane & 15;

  __shared__ __align__(16) f16 Ks[64][136];
  __shared__ __align__(16) f16 Vs[128][72];
  __shared__ __align__(16) int As[64][68];
  __shared__ __align__(16) f16 Ps[4][16][72];

  f16x8 qf[4];
#pragma unroll
  for (int ks = 0; ks < 4; ++ks)
    qf[ks] = *(const f16x8*)(Q + (size_t)(qb + wave * 16 + l16) * 128 + ks * 32 + quad * 8);
  f16x8 ONES;
#pragma unroll
  for (int j = 0; j < 8; ++j) ONES[j] = (f16)1.0f;

  f32x4 Oacc[8];
#pragma unroll
  for (int ot = 0; ot < 8; ++ot) Oacc[ot] = (f32x4){0.f, 0.f, 0.f, 0.f};
  f32x4 Lacc = (f32x4){0.f, 0.f, 0.f, 0.f};
  float m2[4];
#pragma unroll
  for (int r = 0; r < 4; ++r) m2[r] = -INFINITY;

  i32x4 pK[4], pV[4], pA[4];
#pragma unroll
  for (int i = 0; i < 4; ++i) {
    int c = i * 256 + tid;
    pK[i] = *(const i32x4*)(Kg + (size_t)(c >> 4) * 128 + (c & 15) * 8);
    pV[i] = *(const i32x4*)(Vt + (size_t)(c >> 3) * N_TOK + (c & 7) * 8);
    pA[i] = *(const i32x4*)(adj + (size_t)(qb + (c >> 4)) * N_TOK + (c & 15) * 4);
  }

  for (int it = 0; it < 256; ++it) {
    __syncthreads();
#pragma unroll
    for (int i = 0; i < 4; ++i) {
      int c = i * 256 + tid;
      *(f16x8*)(&Ks[c >> 4][(c & 15) * 8]) = __builtin_bit_cast(f16x8, pK[i]);
      *(f16x8*)(&Vs[c >> 3][(c & 7) * 8])  = __builtin_bit_cast(f16x8, pV[i]);
      *(i32x4*)(&As[c >> 4][(c & 15) * 4]) = pA[i];
    }
    __syncthreads();
    if (it + 1 < 256) {
      int kb = (it + 1) * 64;
#pragma unroll
      for (int i = 0; i < 4; ++i) {
        int c = i * 256 + tid;
        pK[i] = *(const i32x4*)(Kg + (size_t)(kb + (c >> 4)) * 128 + (c & 15) * 8);
        pV[i] = *(const i32x4*)(Vt + (size_t)(c >> 3) * N_TOK + kb + (c & 7) * 8);
        pA[i] = *(const i32x4*)(adj + (size_t)(qb + (c >> 4)) * N_TOK + kb + (c & 15) * 4);
      }
    }
    float sc[4][4];
#pragma unroll
    for (int ct = 0; ct < 4; ++ct) {
      f32x4 s = (f32x4){0.f, 0.f, 0.f, 0.f};
#pragma unroll
      for (int ks = 0; ks < 4; ++ks) {
        f16x8 b = *(const f16x8*)(&Ks[ct * 16 + l16][ks * 32 + quad * 8]);
        s = __builtin_amdgcn_mfma_f32_16x16x32_f16(qf[ks], b, s, 0, 0, 0);
      }
#pragma unroll
      for (int r = 0; r < 4; ++r) {
        float v = s[r];
        v = fmaxf(v, ALPHA_LRELU * v);
        sc[ct][r] = (As[wave * 16 + quad * 4 + r][ct * 16 + l16] > 0) ? v : NEGV;
      }
    }
    float mx[4];
#pragma unroll
    for (int r = 0; r < 4; ++r) {
      float m = fmaxf(fmaxf(sc[0][r], sc[1][r]), fmaxf(sc[2][r], sc[3][r]));
#pragma unroll
      for (int off = 8; off >= 1; off >>= 1)
        m = fmaxf(m, __shfl_xor(m, off, 16));
      mx[r] = m;
    }
    bool up = (mx[0] > m2[0]) | (mx[1] > m2[1]) | (mx[2] > m2[2]) | (mx[3] > m2[3]);
    if (__ballot(up)) {
      float al[4];
#pragma unroll
      for (int r = 0; r < 4; ++r) {
        float mn = fmaxf(m2[r], mx[r]);
        al[r] = exp2f(m2[r] - mn);
        m2[r] = mn;
      }
#pragma unroll
      for (int ot = 0; ot < 8; ++ot)
#pragma unroll
        for (int r = 0; r < 4; ++r) Oacc[ot][r] *= al[r];
#pragma unroll
      for (int r = 0; r < 4; ++r) Lacc[r] *= al[r];
    }
#pragma unroll
    for (int ct = 0; ct < 4; ++ct)
#pragma unroll
      for (int r = 0; r < 4; ++r)
        Ps[wave][quad * 4 + r][ct * 16 + l16] = (f16)exp2f(sc[ct][r] - m2[r]);

    asm volatile("s_waitcnt lgkmcnt(0)" ::: "memory");
    f16x8 pa0 = *(const f16x8*)(&Ps[wave][l16][quad * 8]);
    f16x8 pa1 = *(const f16x8*)(&Ps[wave][l16][32 + quad * 8]);
#pragma unroll
    for (int ot = 0; ot < 8; ++ot) {
      f16x8 b0 = *(const f16x8*)(&Vs[ot * 16 + l16][quad * 8]);
      f16x8 b1 = *(const f16x8*)(&Vs[ot * 16 + l16][32 + quad * 8]);
      Oacc[ot] = __builtin_amdgcn_mfma_f32_16x16x32_f16(pa0, b0, Oacc[ot], 0, 0, 0);
      Oacc[ot] = __builtin_amdgcn_mfma_f32_16x16x32_f16(pa1, b1, Oacc[ot], 0, 0, 0);
    }
    Lacc = __builtin_amdgcn_mfma_f32_16x16x32_f16(pa0, ONES, Lacc, 0, 0, 0);
    Lacc = __builtin_amdgcn_mfma_f32_16x16x32_f16(pa1, ONES, Lacc, 0, 0, 0);
  }
#pragma unroll
  for (int ot = 0; ot < 8; ++ot)
#pragma unroll
    for (int r = 0; r < 4; ++r) {
      float v = Oacc[ot][r] / Lacc[r];
      v = (v > 0.f) ? v : (__expf(v) - 1.f);
      int row = qb + wave * 16 + quad * 4 + r;
      out[(size_t)row * 128 + ot * 16 + l16] = v;
    }
}

extern "C" void kernel_launch(void* const* d_in, const int* in_sizes, int n_in,
                              void* d_out, int out_size, void* d_ws, size_t ws_size,
                              hipStream_t stream)
{
  const void* h  = d_in[0];
  const int* adj = (const int*)d_in[1];
  const void* Wq = d_in[2];
  const void* Wk = d_in[3];
  const void* Wv = d_in[4];
  float* out = (float*)d_out;             // fp32 [16384][128]

  char* ws = (char*)d_ws;
  int* flag = (int*)ws;                    // @0
  f16* Wt = (f16*)(ws + 1024);             // 196608 B
  f16* Q  = (f16*)(ws + 262144);           // 4 MiB
  f16* K  = (f16*)(ws + 4456448);          // 4 MiB
  f16* Vt = (f16*)(ws + 8650752);          // 4 MiB -> 12845056
  float* Opart = (float*)(ws + 12845056);  // 3 x 16384 x 128 f32 = 24 MiB
  float* mpart = (float*)(ws + 38010880);  // 3 x 16384 f32
  float* lpart = (float*)(ws + 38207488);  // 3 x 16384 f32 -> 38404096
  const size_t NEED_BASE  = 12845056;
  const size_t NEED_SPLIT = 38404096;

  if (ws_size < NEED_BASE) {
    sentinel_kernel<<<(N_TOK * 128 + 255) / 256, 256, 0, stream>>>(out);
    return;
  }

  detect_kernel<<<1, 64, 0, stream>>>((const u16*)h, flag);
  wt_kernel<<<dim3(128, 3), 256, 0, stream>>>(flag, Wq, Wk, Wv, Wt);
  qkv_kernel<<<dim3(256, 3), 256, 0, stream>>>(flag, h, Wt, Q, K, Vt);

  if (ws_size >= NEED_SPLIT) {
    // split-K x3: 768 blocks -> exactly 3 blocks/CU (LDS 44.5 KB/block)
    flash_kernel<<<dim3(256, NSPLIT), 256, 0, stream>>>(Q, K, Vt, adj,
                                                        Opart, mpart, lpart);
    combine_kernel<<<dim3(256), 256, 0, stream>>>(Opart, mpart, lpart, out);
  } else {
    flash1_kernel<<<dim3(256), 256, 0, stream>>>(Q, K, Vt, adj, out);
  }
}

// Round 3
// 1598.330 us; speedup vs baseline: 1.4407x; 1.1172x over previous
//
#include <hip/hip_runtime.h>

#define N_TOK 16384
#define ALPHA_LRELU 0.2f
#define NEGV -9e15f
#define NSPLIT 3
#define LOG2E 1.44269504f

typedef _Float16 f16;
typedef __attribute__((ext_vector_type(8))) _Float16 f16x8;
typedef __attribute__((ext_vector_type(4))) float f32x4;
typedef __attribute__((ext_vector_type(4))) int i32x4;
typedef unsigned short u16;

__device__ __forceinline__ float bf2f(u16 b) {
  unsigned u = ((unsigned)b) << 16;
  return __builtin_bit_cast(float, u);
}
__device__ __forceinline__ f16x8 cvt8(i32x4 v) {
  f16x8 r;
#pragma unroll
  for (int i = 0; i < 4; ++i) {
    unsigned u = __builtin_bit_cast(unsigned, v[i]);
    r[2 * i]     = (f16)__builtin_bit_cast(float, (u & 0xffffu) << 16);
    r[2 * i + 1] = (f16)__builtin_bit_cast(float, u & 0xffff0000u);
  }
  return r;
}

// ---------------- kernel 0: input dtype detection (EVEN u16 parity) ----
__global__ __launch_bounds__(64) void detect_kernel(const u16* __restrict__ h16,
                                                    int* __restrict__ flag)
{
  int lane = threadIdx.x;
  unsigned u = h16[lane * 2];
  unsigned e = (u >> 7) & 0xFFu;
  int sane = (e >= 0x60u && e <= 0x8Eu) ? 1 : 0;
#pragma unroll
  for (int off = 32; off >= 1; off >>= 1) sane += __shfl_xor(sane, off);
  if (lane == 0) *flag = (sane >= 32) ? 1 : 0;  // 1 = bf16 inputs, 0 = fp32
}

// ---------------- kernel 0.5: ws-too-small sentinel ----------------
__global__ __launch_bounds__(256) void sentinel_kernel(float* __restrict__ out) {
  int i = blockIdx.x * 256 + threadIdx.x;
  if (i < N_TOK * 128) out[i] = 100.0f;
}

// ---------------- kernel 1: W transpose -> fp16 ----------------
// W_query additionally scaled by log2(e): scores arrive in log2 domain
// (leakyrelu commutes with positive scaling), so softmax uses exp2 directly.
__global__ __launch_bounds__(256) void wt_kernel(
    const int* __restrict__ flag,
    const void* __restrict__ Wq, const void* __restrict__ Wk,
    const void* __restrict__ Wv, f16* __restrict__ Wt)
{
  const int isbf = *flag;
  int w = blockIdx.y;
  const void* W = (w == 0) ? Wq : (w == 1) ? Wk : Wv;
  int idx = blockIdx.x * 256 + threadIdx.x;
  int k = idx >> 7, n = idx & 127;
  float v = isbf ? bf2f(((const u16*)W)[idx]) : ((const float*)W)[idx];
  if (w == 0) v *= LOG2E;
  Wt[w * 32768 + n * 256 + k] = (f16)v;
}

// ---------------- kernel 2: fused QKV GEMM ----------------
__global__ __launch_bounds__(256) void qkv_kernel(
    const int* __restrict__ flag, const void* __restrict__ hvp,
    const f16* __restrict__ Wt,
    f16* __restrict__ Qo, f16* __restrict__ Ko, f16* __restrict__ Vt)
{
  const int isbf = *flag;
  const int mb = blockIdx.x * 64;
  const int gy = blockIdx.y;
  const int tid = threadIdx.x;
  const int wave = tid >> 6, lane = tid & 63, quad = lane >> 4, l16 = lane & 15;

  __shared__ __align__(16) f16 hs[64][256 + 8];

  if (isbf) {
    const u16* h = (const u16*)hvp;
#pragma unroll
    for (int i = 0; i < 8; ++i) {
      int c = i * 256 + tid;
      int r = c >> 5, o = c & 31;
      i32x4 v = *(const i32x4*)(h + (size_t)(mb + r) * 256 + o * 8);
      *(f16x8*)(&hs[r][o * 8]) = cvt8(v);
    }
  } else {
    const float* h = (const float*)hvp;
#pragma unroll
    for (int i = 0; i < 8; ++i) {
      int c = i * 256 + tid;
      int r = c >> 5, o = c & 31;
      const float* p = h + (size_t)(mb + r) * 256 + o * 8;
      f32x4 v0 = *(const f32x4*)p, v1 = *(const f32x4*)(p + 4);
      f16x8 q;
#pragma unroll
      for (int j = 0; j < 4; ++j) { q[j] = (f16)v0[j]; q[4 + j] = (f16)v1[j]; }
      *(f16x8*)(&hs[r][o * 8]) = q;
    }
  }
  __syncthreads();

  const f16* Wg = Wt + gy * 32768;

  if (gy < 2) {
    f16x8 a[8];
#pragma unroll
    for (int ks = 0; ks < 8; ++ks)
      a[ks] = *(const f16x8*)(&hs[wave * 16 + l16][ks * 32 + quad * 8]);
    f32x4 acc[8];
#pragma unroll
    for (int ct = 0; ct < 8; ++ct) acc[ct] = (f32x4){0.f, 0.f, 0.f, 0.f};
#pragma unroll
    for (int ks = 0; ks < 8; ++ks)
#pragma unroll
      for (int ct = 0; ct < 8; ++ct) {
        f16x8 b = *(const f16x8*)(Wg + (ct * 16 + l16) * 256 + ks * 32 + quad * 8);
        acc[ct] = __builtin_amdgcn_mfma_f32_16x16x32_f16(a[ks], b, acc[ct], 0, 0, 0);
      }
    f16* O = (gy == 0) ? Qo : Ko;
#pragma unroll
    for (int ct = 0; ct < 8; ++ct)
#pragma unroll
      for (int r = 0; r < 4; ++r)
        O[(size_t)(mb + wave * 16 + quad * 4 + r) * 128 + ct * 16 + l16] = (f16)acc[ct][r];
  } else {
    f32x4 acc[2][4];
#pragma unroll
    for (int ft = 0; ft < 2; ++ft)
#pragma unroll
      for (int bt = 0; bt < 4; ++bt) acc[ft][bt] = (f32x4){0.f, 0.f, 0.f, 0.f};
#pragma unroll
    for (int ks = 0; ks < 8; ++ks) {
      f16x8 a2[2], b2[4];
#pragma unroll
      for (int ft = 0; ft < 2; ++ft)
        a2[ft] = *(const f16x8*)(Wg + ((wave * 2 + ft) * 16 + l16) * 256 + ks * 32 + quad * 8);
#pragma unroll
      for (int bt = 0; bt < 4; ++bt)
        b2[bt] = *(const f16x8*)(&hs[bt * 16 + l16][ks * 32 + quad * 8]);
#pragma unroll
      for (int ft = 0; ft < 2; ++ft)
#pragma unroll
        for (int bt = 0; bt < 4; ++bt)
          acc[ft][bt] = __builtin_amdgcn_mfma_f32_16x16x32_f16(a2[ft], b2[bt], acc[ft][bt], 0, 0, 0);
    }
#pragma unroll
    for (int ft = 0; ft < 2; ++ft)
#pragma unroll
      for (int bt = 0; bt < 4; ++bt)
#pragma unroll
        for (int r = 0; r < 4; ++r)
          Vt[(size_t)((wave * 2 + ft) * 16 + quad * 4 + r) * N_TOK + mb + bt * 16 + l16] =
              (f16)acc[ft][bt][r];
  }
}

// ---------------- kernel 3: flash attention, split-K x3, log2 domain ----
// adjacency ballot-packed to 1 bit in LDS: As16[64][4] (512 B).
// REGISTER LAW (gfx950 unified VGPR/AGPR file; VGPR_Count reports arch half):
//   r1: (256,3) cap=170 total -> 84+84=168, spilled prefetch (catastrophic).
//   r2: no cap -> 132+132=264 > 256 -> 1 wave/SIMD, Occupancy 11.8%, stalls.
//   now: (256,2) cap=256 total -> allocator shaves 8 regs, 2 waves/SIMD.
__global__ __launch_bounds__(256, 2) void flash_kernel(
    const f16* __restrict__ Q, const f16* __restrict__ Kg,
    const f16* __restrict__ Vt, const int* __restrict__ adj,
    float* __restrict__ Opart, float* __restrict__ mpart,
    float* __restrict__ lpart)
{
  const int qb = blockIdx.x * 64;
  const int ksec = blockIdx.y;
  const int base = 256 / NSPLIT;                 // 85
  const int rem  = 256 % NSPLIT;                 // 1
  const int iters = base + (ksec < rem ? 1 : 0); // 86,85,85
  const int tile0 = ksec * base + (ksec < rem ? ksec : rem);
  const int kb0 = tile0 * 64;
  const int tid = threadIdx.x;
  const int wave = tid >> 6, lane = tid & 63, quad = lane >> 4, l16 = lane & 15;

  __shared__ __align__(16) f16 Ks[64][136];
  __shared__ __align__(16) f16 Vs[128][72];
  __shared__ __align__(16) f16 Ps[4][16][72];
  __shared__ __align__(8)  u16 As16[64][4];

  f16x8 qf[4];
#pragma unroll
  for (int ks = 0; ks < 4; ++ks)
    qf[ks] = *(const f16x8*)(Q + (size_t)(qb + wave * 16 + l16) * 128 + ks * 32 + quad * 8);

  f16x8 ONES;
#pragma unroll
  for (int j = 0; j < 8; ++j) ONES[j] = (f16)1.0f;

  // mask-bit query shift: bit (l16&3)*16 + ct*4 + (l16>>2) of the packed row
  const int shq = (l16 & 3) * 16 + (l16 >> 2);

  f32x4 Oacc[8];
#pragma unroll
  for (int ot = 0; ot < 8; ++ot) Oacc[ot] = (f32x4){0.f, 0.f, 0.f, 0.f};
  f32x4 Lacc = (f32x4){0.f, 0.f, 0.f, 0.f};  // row-sum via MFMA-ones
  float m2[4];
#pragma unroll
  for (int r = 0; r < 4; ++r) m2[r] = -INFINITY;

  i32x4 pK[4], pV[4], pA[4];
#pragma unroll
  for (int i = 0; i < 4; ++i) {
    int c = i * 256 + tid;
    pK[i] = *(const i32x4*)(Kg + (size_t)(kb0 + (c >> 4)) * 128 + (c & 15) * 8);
    pV[i] = *(const i32x4*)(Vt + (size_t)(c >> 3) * N_TOK + kb0 + (c & 7) * 8);
    pA[i] = *(const i32x4*)(adj + (size_t)(qb + (c >> 4)) * N_TOK + kb0 + (c & 15) * 4);
  }

  for (int it = 0; it < iters; ++it) {
    __syncthreads();
#pragma unroll
    for (int i = 0; i < 4; ++i) {
      int c = i * 256 + tid;
      *(f16x8*)(&Ks[c >> 4][(c & 15) * 8]) = __builtin_bit_cast(f16x8, pK[i]);
      *(f16x8*)(&Vs[c >> 3][(c & 7) * 8])  = __builtin_bit_cast(f16x8, pV[i]);
      // ballot-pack adjacency: bit l of b_j = adj[row(i,wave,l>>4)][col (l&15)*4+j]
      unsigned long long b0 = __ballot(pA[i][0] > 0);
      unsigned long long b1 = __ballot(pA[i][1] > 0);
      unsigned long long b2 = __ballot(pA[i][2] > 0);
      unsigned long long b3 = __ballot(pA[i][3] > 0);
      if (lane < 16) {
        int j = lane & 3, g = lane >> 2;
        unsigned long long v = (j == 0) ? b0 : (j == 1) ? b1 : (j == 2) ? b2 : b3;
        As16[i * 16 + wave * 4 + g][j] = (u16)(v >> (16 * g));
      }
    }
    __syncthreads();
    if (it + 1 < iters) {
      int kb = kb0 + (it + 1) * 64;
#pragma unroll
      for (int i = 0; i < 4; ++i) {
        int c = i * 256 + tid;
        pK[i] = *(const i32x4*)(Kg + (size_t)(kb + (c >> 4)) * 128 + (c & 15) * 8);
        pV[i] = *(const i32x4*)(Vt + (size_t)(c >> 3) * N_TOK + kb + (c & 7) * 8);
        pA[i] = *(const i32x4*)(adj + (size_t)(qb + (c >> 4)) * N_TOK + kb + (c & 15) * 4);
      }
    }

    // S(log2 domain) = Q K^T, leakyrelu
    float sc[4][4];
#pragma unroll
    for (int ct = 0; ct < 4; ++ct) {
      f32x4 s = (f32x4){0.f, 0.f, 0.f, 0.f};
#pragma unroll
      for (int ks = 0; ks < 4; ++ks) {
        f16x8 b = *(const f16x8*)(&Ks[ct * 16 + l16][ks * 32 + quad * 8]);
        s = __builtin_amdgcn_mfma_f32_16x16x32_f16(qf[ks], b, s, 0, 0, 0);
      }
#pragma unroll
      for (int r = 0; r < 4; ++r) {
        float v = s[r];
        sc[ct][r] = fmaxf(v, ALPHA_LRELU * v);
      }
    }
    // adjacency mask from packed bits (broadcast b64 read per row)
#pragma unroll
    for (int r = 0; r < 4; ++r) {
      unsigned long long a64 =
          *(const unsigned long long*)(&As16[wave * 16 + quad * 4 + r][0]);
      unsigned y = (unsigned)(a64 >> shq);
#pragma unroll
      for (int ct = 0; ct < 4; ++ct)
        if (!((y >> (4 * ct)) & 1u)) sc[ct][r] = NEGV;
    }

    // tile row max (16-lane butterfly within quad)
    float mx[4];
#pragma unroll
    for (int r = 0; r < 4; ++r) {
      float m = fmaxf(fmaxf(sc[0][r], sc[1][r]), fmaxf(sc[2][r], sc[3][r]));
#pragma unroll
      for (int off = 8; off >= 1; off >>= 1)
        m = fmaxf(m, __shfl_xor(m, off, 16));
      mx[r] = m;
    }
    // wave-uniform skip: rescale only if some row's max improved
    bool up = (mx[0] > m2[0]) | (mx[1] > m2[1]) | (mx[2] > m2[2]) | (mx[3] > m2[3]);
    if (__ballot(up)) {
      float al[4];
#pragma unroll
      for (int r = 0; r < 4; ++r) {
        float mn = fmaxf(m2[r], mx[r]);
        al[r] = exp2f(m2[r] - mn);
        m2[r] = mn;
      }
#pragma unroll
      for (int ot = 0; ot < 8; ++ot)
#pragma unroll
        for (int r = 0; r < 4; ++r) Oacc[ot][r] *= al[r];
#pragma unroll
      for (int r = 0; r < 4; ++r) Lacc[r] *= al[r];
    }

    // P = exp2(sc - m2), to LDS (C-layout -> A-layout round trip)
#pragma unroll
    for (int ct = 0; ct < 4; ++ct)
#pragma unroll
      for (int r = 0; r < 4; ++r)
        Ps[wave][quad * 4 + r][ct * 16 + l16] = (f16)exp2f(sc[ct][r] - m2[r]);

    asm volatile("s_waitcnt lgkmcnt(0)" ::: "memory");
    f16x8 pa0 = *(const f16x8*)(&Ps[wave][l16][quad * 8]);
    f16x8 pa1 = *(const f16x8*)(&Ps[wave][l16][32 + quad * 8]);
#pragma unroll
    for (int ot = 0; ot < 8; ++ot) {
      f16x8 b0 = *(const f16x8*)(&Vs[ot * 16 + l16][quad * 8]);
      f16x8 b1 = *(const f16x8*)(&Vs[ot * 16 + l16][32 + quad * 8]);
      Oacc[ot] = __builtin_amdgcn_mfma_f32_16x16x32_f16(pa0, b0, Oacc[ot], 0, 0, 0);
      Oacc[ot] = __builtin_amdgcn_mfma_f32_16x16x32_f16(pa1, b1, Oacc[ot], 0, 0, 0);
    }
    // row-sum of P via all-ones B (every lane gets the sum)
    Lacc = __builtin_amdgcn_mfma_f32_16x16x32_f16(pa0, ONES, Lacc, 0, 0, 0);
    Lacc = __builtin_amdgcn_mfma_f32_16x16x32_f16(pa1, ONES, Lacc, 0, 0, 0);
  }

  float* Op = Opart + (size_t)ksec * (N_TOK * 128);
#pragma unroll
  for (int ot = 0; ot < 8; ++ot)
#pragma unroll
    for (int r = 0; r < 4; ++r) {
      int row = qb + wave * 16 + quad * 4 + r;
      Op[(size_t)row * 128 + ot * 16 + l16] = Oacc[ot][r];
    }
  if (l16 == 0) {
#pragma unroll
    for (int r = 0; r < 4; ++r) {
      int row = qb + wave * 16 + quad * 4 + r;
      mpart[ksec * N_TOK + row] = m2[r];   // log2-domain max
      lpart[ksec * N_TOK + row] = Lacc[r];
    }
  }
}

// ---------------- kernel 4: split-K combine + elu (log2 domain) --------
__global__ __launch_bounds__(256) void combine_kernel(
    const float* __restrict__ Opart, const float* __restrict__ mpart,
    const float* __restrict__ lpart, float* __restrict__ out)
{
  const int qb = blockIdx.x * 64;
  const int t = threadIdx.x;
  __shared__ float sa[NSPLIT][64], sdn[64];
  if (t < 64) {
    float m = -INFINITY;
#pragma unroll
    for (int s = 0; s < NSPLIT; ++s) m = fmaxf(m, mpart[s * N_TOK + qb + t]);
    float dn = 0.f;
#pragma unroll
    for (int s = 0; s < NSPLIT; ++s) {
      float a = exp2f(mpart[s * N_TOK + qb + t] - m);
      sa[s][t] = a;
      dn += lpart[s * N_TOK + qb + t] * a;
    }
    sdn[t] = 1.0f / dn;
  }
  __syncthreads();
  float* Og = out + (size_t)qb * 128;
#pragma unroll
  for (int i = 0; i < 8; ++i) {
    int idx = (i * 256 + t) * 4;
    int row = idx >> 7;
    f32x4 acc = (f32x4){0.f, 0.f, 0.f, 0.f};
#pragma unroll
    for (int s = 0; s < NSPLIT; ++s) {
      f32x4 o = *(const f32x4*)(Opart + (size_t)s * (N_TOK * 128) + (size_t)qb * 128 + idx);
      float a = sa[s][row];
#pragma unroll
      for (int j = 0; j < 4; ++j) acc[j] += o[j] * a;
    }
    float dn = sdn[row];
    f32x4 v;
#pragma unroll
    for (int j = 0; j < 4; ++j) {
      float x = acc[j] * dn;
      v[j] = (x > 0.f) ? x : (__expf(x) - 1.f);
    }
    *(f32x4*)(Og + idx) = v;
  }
}

// ---------------- fallback: single-pass flash (ws too small) ----------
__global__ __launch_bounds__(256) void flash1_kernel(
    const f16* __restrict__ Q, const f16* __restrict__ Kg,
    const f16* __restrict__ Vt, const int* __restrict__ adj,
    float* __restrict__ out)
{
  const int qb = blockIdx.x * 64;
  const int tid = threadIdx.x;
  const int wave = tid >> 6, lane = tid & 63, quad = lane >> 4, l16 = lane & 15;

  __shared__ __align__(16) f16 Ks[64][136];
  __shared__ __align__(16) f16 Vs[128][72];
  __shared__ __align__(16) int As[64][68];
  __shared__ __align__(16) f16 Ps[4][16][72];

  f16x8 qf[4];
#pragma unroll
  for (int ks = 0; ks < 4; ++ks)
    qf[ks] = *(const f16x8*)(Q + (size_t)(qb + wave * 16 + l16) * 128 + ks * 32 + quad * 8);
  f16x8 ONES;
#pragma unroll
  for (int j = 0; j < 8; ++j) ONES[j] = (f16)1.0f;

  f32x4 Oacc[8];
#pragma unroll
  for (int ot = 0; ot < 8; ++ot) Oacc[ot] = (f32x4){0.f, 0.f, 0.f, 0.f};
  f32x4 Lacc = (f32x4){0.f, 0.f, 0.f, 0.f};
  float m2[4];
#pragma unroll
  for (int r = 0; r < 4; ++r) m2[r] = -INFINITY;

  i32x4 pK[4], pV[4], pA[4];
#pragma unroll
  for (int i = 0; i < 4; ++i) {
    int c = i * 256 + tid;
    pK[i] = *(const i32x4*)(Kg + (size_t)(c >> 4) * 128 + (c & 15) * 8);
    pV[i] = *(const i32x4*)(Vt + (size_t)(c >> 3) * N_TOK + (c & 7) * 8);
    pA[i] = *(const i32x4*)(adj + (size_t)(qb + (c >> 4)) * N_TOK + (c & 15) * 4);
  }

  for (int it = 0; it < 256; ++it) {
    __syncthreads();
#pragma unroll
    for (int i = 0; i < 4; ++i) {
      int c = i * 256 + tid;
      *(f16x8*)(&Ks[c >> 4][(c & 15) * 8]) = __builtin_bit_cast(f16x8, pK[i]);
      *(f16x8*)(&Vs[c >> 3][(c & 7) * 8])  = __builtin_bit_cast(f16x8, pV[i]);
      *(i32x4*)(&As[c >> 4][(c & 15) * 4]) = pA[i];
    }
    __syncthreads();
    if (it + 1 < 256) {
      int kb = (it + 1) * 64;
#pragma unroll
      for (int i = 0; i < 4; ++i) {
        int c = i * 256 + tid;
        pK[i] = *(const i32x4*)(Kg + (size_t)(kb + (c >> 4)) * 128 + (c & 15) * 8);
        pV[i] = *(const i32x4*)(Vt + (size_t)(c >> 3) * N_TOK + kb + (c & 7) * 8);
        pA[i] = *(const i32x4*)(adj + (size_t)(qb + (c >> 4)) * N_TOK + kb + (c & 15) * 4);
      }
    }
    float sc[4][4];
#pragma unroll
    for (int ct = 0; ct < 4; ++ct) {
      f32x4 s = (f32x4){0.f, 0.f, 0.f, 0.f};
#pragma unroll
      for (int ks = 0; ks < 4; ++ks) {
        f16x8 b = *(const f16x8*)(&Ks[ct * 16 + l16][ks * 32 + quad * 8]);
        s = __builtin_amdgcn_mfma_f32_16x16x32_f16(qf[ks], b, s, 0, 0, 0);
      }
#pragma unroll
      for (int r = 0; r < 4; ++r) {
        float v = s[r];
        v = fmaxf(v, ALPHA_LRELU * v);
        sc[ct][r] = (As[wave * 16 + quad * 4 + r][ct * 16 + l16] > 0) ? v : NEGV;
      }
    }
    float mx[4];
#pragma unroll
    for (int r = 0; r < 4; ++r) {
      float m = fmaxf(fmaxf(sc[0][r], sc[1][r]), fmaxf(sc[2][r], sc[3][r]));
#pragma unroll
      for (int off = 8; off >= 1; off >>= 1)
        m = fmaxf(m, __shfl_xor(m, off, 16));
      mx[r] = m;
    }
    bool up = (mx[0] > m2[0]) | (mx[1] > m2[1]) | (mx[2] > m2[2]) | (mx[3] > m2[3]);
    if (__ballot(up)) {
      float al[4];
#pragma unroll
      for (int r = 0; r < 4; ++r) {
        float mn = fmaxf(m2[r], mx[r]);
        al[r] = exp2f(m2[r] - mn);
        m2[r] = mn;
      }
#pragma unroll
      for (int ot = 0; ot < 8; ++ot)
#pragma unroll
        for (int r = 0; r < 4; ++r) Oacc[ot][r] *= al[r];
#pragma unroll
      for (int r = 0; r < 4; ++r) Lacc[r] *= al[r];
    }
#pragma unroll
    for (int ct = 0; ct < 4; ++ct)
#pragma unroll
      for (int r = 0; r < 4; ++r)
        Ps[wave][quad * 4 + r][ct * 16 + l16] = (f16)exp2f(sc[ct][r] - m2[r]);

    asm volatile("s_waitcnt lgkmcnt(0)" ::: "memory");
    f16x8 pa0 = *(const f16x8*)(&Ps[wave][l16][quad * 8]);
    f16x8 pa1 = *(const f16x8*)(&Ps[wave][l16][32 + quad * 8]);
#pragma unroll
    for (int ot = 0; ot < 8; ++ot) {
      f16x8 b0 = *(const f16x8*)(&Vs[ot * 16 + l16][quad * 8]);
      f16x8 b1 = *(const f16x8*)(&Vs[ot * 16 + l16][32 + quad * 8]);
      Oacc[ot] = __builtin_amdgcn_mfma_f32_16x16x32_f16(pa0, b0, Oacc[ot], 0, 0, 0);
      Oacc[ot] = __builtin_amdgcn_mfma_f32_16x16x32_f16(pa1, b1, Oacc[ot], 0, 0, 0);
    }
    Lacc = __builtin_amdgcn_mfma_f32_16x16x32_f16(pa0, ONES, Lacc, 0, 0, 0);
    Lacc = __builtin_amdgcn_mfma_f32_16x16x32_f16(pa1, ONES, Lacc, 0, 0, 0);
  }
#pragma unroll
  for (int ot = 0; ot < 8; ++ot)
#pragma unroll
    for (int r = 0; r < 4; ++r) {
      float v = Oacc[ot][r] / Lacc[r];
      v = (v > 0.f) ? v : (__expf(v) - 1.f);
      int row = qb + wave * 16 + quad * 4 + r;
      out[(size_t)row * 128 + ot * 16 + l16] = v;
    }
}

extern "C" void kernel_launch(void* const* d_in, const int* in_sizes, int n_in,
                              void* d_out, int out_size, void* d_ws, size_t ws_size,
                              hipStream_t stream)
{
  const void* h  = d_in[0];
  const int* adj = (const int*)d_in[1];
  const void* Wq = d_in[2];
  const void* Wk = d_in[3];
  const void* Wv = d_in[4];
  float* out = (float*)d_out;             // fp32 [16384][128]

  char* ws = (char*)d_ws;
  int* flag = (int*)ws;                    // @0
  f16* Wt = (f16*)(ws + 1024);             // 196608 B
  f16* Q  = (f16*)(ws + 262144);           // 4 MiB
  f16* K  = (f16*)(ws + 4456448);          // 4 MiB
  f16* Vt = (f16*)(ws + 8650752);          // 4 MiB -> 12845056
  float* Opart = (float*)(ws + 12845056);  // 3 x 16384 x 128 f32 = 24 MiB
  float* mpart = (float*)(ws + 38010880);  // 3 x 16384 f32
  float* lpart = (float*)(ws + 38207488);  // 3 x 16384 f32 -> 38404096
  const size_t NEED_BASE  = 12845056;
  const size_t NEED_SPLIT = 38404096;

  if (ws_size < NEED_BASE) {
    sentinel_kernel<<<(N_TOK * 128 + 255) / 256, 256, 0, stream>>>(out);
    return;
  }

  detect_kernel<<<1, 64, 0, stream>>>((const u16*)h, flag);
  wt_kernel<<<dim3(128, 3), 256, 0, stream>>>(flag, Wq, Wk, Wv, Wt);
  qkv_kernel<<<dim3(256, 3), 256, 0, stream>>>(flag, h, Wt, Q, K, Vt);

  if (ws_size >= NEED_SPLIT) {
    // split-K x3: 768 blocks, 2 blocks/CU resident (reg-capped), fine-grained
    // backfill keeps CUs balanced (255 tile-iters per CU either way)
    flash_kernel<<<dim3(256, NSPLIT), 256, 0, stream>>>(Q, K, Vt, adj,
                                                        Opart, mpart, lpart);
    combine_kernel<<<dim3(256), 256, 0, stream>>>(Opart, mpart, lpart, out);
  } else {
    flash1_kernel<<<dim3(256), 256, 0, stream>>>(Q, K, Vt, adj, out);
  }
}